// Round 1
// baseline (252.900 us; speedup 1.0000x reference)
//
#include <hip/hip_runtime.h>

// Problem dims (fixed by the reference)
constexpr int cB = 32, cT = 15, cV = 100, cD = 768, cN = 160, cAP = 7;
constexpr float cLN_EPS = 1e-12f;
constexpr int VCH = 25;                       // views per chunk-block
constexpr int NCH = (cV + VCH - 1) / VCH;     // 4 chunks

__device__ __forceinline__ void fadd(float* p, float v) {
#if defined(__HIP_DEVICE_COMPILE__)
    unsafeAtomicAdd(p, v);   // global_atomic_add_f32 on gfx950
#else
    (void)p; (void)v;
#endif
}

// Kernel A: out[b,n,:] = step_emb[sid] + LayerNorm(pos_fts @ pos_w + pos_b); zero cnt
__global__ __launch_bounds__(256) void k_init(
    const float* __restrict__ pos_fts,   // [B,N,7]
    const float* __restrict__ step_tab,  // [100,D]
    const float* __restrict__ pos_w,     // [7,D]
    const float* __restrict__ pos_b,     // [D]
    const float* __restrict__ ln_g,      // [D]
    const float* __restrict__ ln_b,      // [D]
    const int*   __restrict__ step_ids,  // [B,N]
    float*       __restrict__ out,       // [B,N,D]
    int*         __restrict__ cnt)       // [B*N]
{
    const int row = blockIdx.x;          // b*N + n
    const int tid = threadIdx.x;
    if (tid == 0) cnt[row] = 0;

    __shared__ float sf[cAP];
    __shared__ float red[32];
    if (tid < cAP) sf[tid] = pos_fts[row * cAP + tid];
    __syncthreads();

    float x[3];
    float s = 0.f, ss = 0.f;
#pragma unroll
    for (int j = 0; j < 3; ++j) {
        const int d = tid + j * 256;
        float acc = pos_b[d];
#pragma unroll
        for (int k = 0; k < cAP; ++k) acc = fmaf(sf[k], pos_w[k * cD + d], acc);
        x[j] = acc;
        s += acc; ss += acc * acc;
    }
    // wave reduce (64 lanes) then cross-wave via LDS
    for (int off = 32; off; off >>= 1) {
        s  += __shfl_down(s,  off, 64);
        ss += __shfl_down(ss, off, 64);
    }
    const int wid = tid >> 6, lane = tid & 63;
    if (lane == 0) { red[wid * 2] = s; red[wid * 2 + 1] = ss; }
    __syncthreads();
    if (tid == 0) {
        float S = 0.f, SS = 0.f;
        for (int w = 0; w < 4; ++w) { S += red[w * 2]; SS += red[w * 2 + 1]; }
        const float mu  = S / (float)cD;
        const float var = SS / (float)cD - mu * mu;
        red[16] = mu;
        red[17] = rsqrtf(fmaxf(var, 0.f) + cLN_EPS);
    }
    __syncthreads();
    const float mu = red[16], rs = red[17];
    const int sid = step_ids[row];
    const float* se = step_tab + (size_t)sid * cD;
#pragma unroll
    for (int j = 0; j < 3; ++j) {
        const int d = tid + j * 256;
        out[(size_t)row * cD + d] = (x[j] - mu) * rs * ln_g[d] + ln_b[d] + se[d];
    }
}

// Kernel B: count valid candidate views per (b,node), skipping visited nodes and node 0
__global__ __launch_bounds__(128) void k_count(
    const int* __restrict__ vp_lens,   // [B,T]
    const int* __restrict__ vpids,     // [B,T]
    const int* __restrict__ cand_ids,  // [B,T,V]
    int*       __restrict__ cnt)       // [B*N]
{
    const int bt = blockIdx.x;         // b*T + t
    const int b  = bt / cT;
    __shared__ int svp[cT];
    if (threadIdx.x < cT) svp[threadIdx.x] = vpids[b * cT + threadIdx.x];
    __syncthreads();
    const int len = vp_lens[bt];
    const int v = threadIdx.x;
    if (v < len) {                     // len <= 100 < 128 so this also bounds v < V
        const int cand = cand_ids[bt * cV + v];
        bool skip = (cand <= 0) | (cand >= cN);
#pragma unroll
        for (int k = 0; k < cT; ++k) skip |= (cand == svp[k]);
        if (!skip) atomicAdd(&cnt[b * cN + cand], 1);
    }
}

// Kernel C: stream valid emb rows once; accumulate candidate means (atomic f32)
// and visited means directly into out.
__global__ __launch_bounds__(192) void k_main(
    const float4* __restrict__ emb,    // [B*T*V, D/4]
    const int*    __restrict__ vp_lens,
    const int*    __restrict__ vpids,
    const int*    __restrict__ cand_ids,
    const int*    __restrict__ cnt,
    float*        __restrict__ out)    // [B,N,D]
{
    const int gb    = blockIdx.x;
    const int bt    = gb / NCH;
    const int chunk = gb - bt * NCH;
    const int b     = bt / cT;
    const int len   = vp_lens[bt];
    const int start = chunk * VCH;
    if (start >= len) return;
    const int nv  = min(VCH, len - start);
    const int tid = threadIdx.x;       // 0..191, each owns 4 consecutive floats

    __shared__ int   svp[cT];
    __shared__ float sw[VCH];
    __shared__ int   scand[VCH];
    if (tid < cT) svp[tid] = vpids[b * cT + tid];
    __syncthreads();
    if (tid < nv) {
        const int cand = cand_ids[bt * cV + start + tid];
        scand[tid] = cand;
        bool skip = (cand <= 0) | (cand >= cN);
#pragma unroll
        for (int k = 0; k < cT; ++k) skip |= (cand == svp[k]);
        float w = 0.f;
        if (!skip) w = 1.0f / (float)max(cnt[b * cN + cand], 1);
        sw[tid] = w;
    }
    __syncthreads();

    float4 vis = make_float4(0.f, 0.f, 0.f, 0.f);
    const float4* base = emb + (size_t)(bt * cV + start) * (cD / 4);
    for (int i = 0; i < nv; ++i) {
        const float4 x = base[(size_t)i * (cD / 4) + tid];
        vis.x += x.x; vis.y += x.y; vis.z += x.z; vis.w += x.w;
        const float w = sw[i];
        if (w > 0.f) {
            float* o = out + (size_t)(b * cN + scand[i]) * cD + tid * 4;
            fadd(o + 0, x.x * w);
            fadd(o + 1, x.y * w);
            fadd(o + 2, x.z * w);
            fadd(o + 3, x.w * w);
        }
    }
    const int vpid = svp[bt - b * cT];
    if (vpid > 0 && vpid < cN) {
        const float invL = 1.0f / (float)len;
        float* o = out + (size_t)(b * cN + vpid) * cD + tid * 4;
        fadd(o + 0, vis.x * invL);
        fadd(o + 1, vis.y * invL);
        fadd(o + 2, vis.z * invL);
        fadd(o + 3, vis.w * invL);
    }
}

extern "C" void kernel_launch(void* const* d_in, const int* in_sizes, int n_in,
                              void* d_out, int out_size, void* d_ws, size_t ws_size,
                              hipStream_t stream) {
    const float* emb      = (const float*)d_in[0];   // [B,T,V,D]
    const float* pos_fts  = (const float*)d_in[1];   // [B,N,7]
    const float* step_tab = (const float*)d_in[2];   // [100,D]
    const float* pos_w    = (const float*)d_in[3];   // [7,D]
    const float* pos_b    = (const float*)d_in[4];   // [D]
    const float* ln_g     = (const float*)d_in[5];   // [D]
    const float* ln_b     = (const float*)d_in[6];   // [D]
    const int*   vp_lens  = (const int*)d_in[7];     // [B,T]
    const int*   vpids    = (const int*)d_in[8];     // [B,T]
    const int*   cand     = (const int*)d_in[9];     // [B,T,V]
    const int*   step_ids = (const int*)d_in[10];    // [B,N]
    // d_in[11] = gmap_lens — unused by the reference output

    float* out = (float*)d_out;
    int*   cnt = (int*)d_ws;                          // B*N ints = 20 KB

    k_init <<<cB * cN, 256, 0, stream>>>(pos_fts, step_tab, pos_w, pos_b,
                                         ln_g, ln_b, step_ids, out, cnt);
    k_count<<<cB * cT, 128, 0, stream>>>(vp_lens, vpids, cand, cnt);
    k_main <<<cB * cT * NCH, 192, 0, stream>>>((const float4*)emb, vp_lens,
                                               vpids, cand, cnt, out);
}

// Round 3
// 50.639 us; speedup vs baseline: 4.9941x; 4.9941x over previous
//
#include <hip/hip_runtime.h>

// Problem dims (fixed by the reference)
constexpr int cB = 32, cT = 15, cV = 100, cD = 768, cN = 160, cAP = 7;
constexpr int cD4 = cD / 4;                   // 192 float4 per row
constexpr int cBN = cB * cN;                  // 5120 rows
constexpr float cLN_EPS = 1e-12f;

// ---------------------------------------------------------------------------
// Kernel 1: count valid candidate views per (b,node), skipping visited/node-0
__global__ __launch_bounds__(128) void k_count(
    const int* __restrict__ vp_lens,   // [B,T]
    const int* __restrict__ vpids,     // [B,T]
    const int* __restrict__ cand_ids,  // [B,T,V]
    int*       __restrict__ cnt)       // [B*N]   (pre-zeroed)
{
    const int bt = blockIdx.x;         // b*T + t
    const int b  = bt / cT;
    __shared__ int svp[cT];
    if (threadIdx.x < cT) svp[threadIdx.x] = vpids[b * cT + threadIdx.x];
    __syncthreads();
    const int len = vp_lens[bt];
    const int v = threadIdx.x;
    if (v < len) {                     // len <= 100 < 128 bounds v < V
        const int cand = cand_ids[bt * cV + v];
        bool skip = (cand <= 0) | (cand >= cN);
#pragma unroll
        for (int k = 0; k < cT; ++k) skip |= (cand == svp[k]);
        if (!skip) atomicAdd(&cnt[b * cN + cand], 1);
    }
}

// ---------------------------------------------------------------------------
// Kernel 2: exclusive prefix scan of cnt[5120] -> offs[5121]; cur = offs copy
__global__ __launch_bounds__(1024) void k_scan(
    const int* __restrict__ cnt,
    int*       __restrict__ offs,      // [B*N+1]
    int*       __restrict__ cur)       // [B*N]
{
    __shared__ int part[1024];
    const int tid = threadIdx.x;
    const int base = tid * 5;          // 5120 = 1024*5
    int loc[5];
    int s = 0;
#pragma unroll
    for (int i = 0; i < 5; ++i) { loc[i] = s; s += cnt[base + i]; }
    part[tid] = s;
    __syncthreads();
    for (int off = 1; off < 1024; off <<= 1) {
        int v = (tid >= off) ? part[tid - off] : 0;
        __syncthreads();
        part[tid] += v;
        __syncthreads();
    }
    const int excl = (tid == 0) ? 0 : part[tid - 1];
#pragma unroll
    for (int i = 0; i < 5; ++i) {
        offs[base + i] = excl + loc[i];
        cur[base + i]  = excl + loc[i];
    }
    if (tid == 1023) offs[cBN] = part[1023];
}

// ---------------------------------------------------------------------------
// Kernel 3: fill CSR index with contributing view row ids (bt*V + v)
__global__ __launch_bounds__(128) void k_fill(
    const int* __restrict__ vp_lens,
    const int* __restrict__ vpids,
    const int* __restrict__ cand_ids,
    int*       __restrict__ cur,       // [B*N] cursors (= offs copy)
    int*       __restrict__ idx)       // contribution row ids
{
    const int bt = blockIdx.x;
    const int b  = bt / cT;
    __shared__ int svp[cT];
    if (threadIdx.x < cT) svp[threadIdx.x] = vpids[b * cT + threadIdx.x];
    __syncthreads();
    const int len = vp_lens[bt];
    const int v = threadIdx.x;
    if (v < len) {
        const int cand = cand_ids[bt * cV + v];
        bool skip = (cand <= 0) | (cand >= cN);
#pragma unroll
        for (int k = 0; k < cT; ++k) skip |= (cand == svp[k]);
        if (!skip) {
            const int p = atomicAdd(&cur[b * cN + cand], 1);
            idx[p] = bt * cV + v;
        }
    }
}

// ---------------------------------------------------------------------------
// Kernel 4: one block per output row. pos-GEMV + LayerNorm + step emb + gather.
__global__ __launch_bounds__(192) void k_fused(
    const float4* __restrict__ emb,      // [B*T*V, D/4]
    const float*  __restrict__ pos_fts,  // [B,N,7]
    const float4* __restrict__ step_tab, // [100, D/4]
    const float4* __restrict__ pos_w,    // [7, D/4]
    const float4* __restrict__ pos_b,    // [D/4]
    const float4* __restrict__ ln_g,     // [D/4]
    const float4* __restrict__ ln_b,     // [D/4]
    const int*    __restrict__ vp_lens,  // [B,T]
    const int*    __restrict__ vpids,    // [B,T]
    const int*    __restrict__ step_ids, // [B,N]
    const int*    __restrict__ offs,     // [B*N+1]
    const int*    __restrict__ idx,      // CSR index
    float4*       __restrict__ out)      // [B*N, D/4]
{
    const int row = blockIdx.x;          // b*N + n
    const int b   = row / cN;
    const int n   = row - b * cN;
    const int tid = threadIdx.x;         // 0..191, owns float4 slot tid

    __shared__ float sf[cAP];
    __shared__ int   svp[cT];
    __shared__ float red[8];
    if (tid < cAP) sf[tid] = pos_fts[row * cAP + tid];
    if (tid >= 64 && tid < 64 + cT) svp[tid - 64] = vpids[b * cT + (tid - 64)];
    __syncthreads();

    // pos GEMV: 4 outputs per thread
    float4 x = pos_b[tid];
#pragma unroll
    for (int k = 0; k < cAP; ++k) {
        const float4 w = pos_w[k * cD4 + tid];
        const float f = sf[k];
        x.x = fmaf(f, w.x, x.x); x.y = fmaf(f, w.y, x.y);
        x.z = fmaf(f, w.z, x.z); x.w = fmaf(f, w.w, x.w);
    }
    float s  = x.x + x.y + x.z + x.w;
    float ss = x.x * x.x + x.y * x.y + x.z * x.z + x.w * x.w;
    for (int off = 32; off; off >>= 1) {
        s  += __shfl_down(s,  off, 64);
        ss += __shfl_down(ss, off, 64);
    }
    const int wid = tid >> 6, lane = tid & 63;
    if (lane == 0) { red[wid * 2] = s; red[wid * 2 + 1] = ss; }
    __syncthreads();
    if (tid == 0) {
        float S = 0.f, SS = 0.f;
        for (int w = 0; w < 3; ++w) { S += red[w * 2]; SS += red[w * 2 + 1]; }
        const float mu  = S / (float)cD;
        const float var = SS / (float)cD - mu * mu;
        red[6] = mu;
        red[7] = rsqrtf(fmaxf(var, 0.f) + cLN_EPS);
    }
    __syncthreads();
    const float mu = red[6], rs = red[7];

    // ---- gather image feature for this node ----
    float ax = 0.f, ay = 0.f, az = 0.f, aw = 0.f;
    float wgt = 0.f;
    if (n > 0) {
        int tvis = -1;
#pragma unroll
        for (int k = cT - 1; k >= 0; --k) if (tvis < 0 && svp[k] == n) tvis = k;
        if (tvis >= 0) {
            // visited node: mean over valid views of step tvis
            const int bt  = b * cT + tvis;
            const int len = vp_lens[bt];
            const float4* base = emb + (size_t)bt * cV * cD4 + tid;
            int i = 0;
            for (; i + 4 <= len; i += 4) {
                const float4 a0 = base[(size_t)(i + 0) * cD4];
                const float4 a1 = base[(size_t)(i + 1) * cD4];
                const float4 a2 = base[(size_t)(i + 2) * cD4];
                const float4 a3 = base[(size_t)(i + 3) * cD4];
                ax += (a0.x + a1.x) + (a2.x + a3.x);
                ay += (a0.y + a1.y) + (a2.y + a3.y);
                az += (a0.z + a1.z) + (a2.z + a3.z);
                aw += (a0.w + a1.w) + (a2.w + a3.w);
            }
            for (; i < len; ++i) {
                const float4 a0 = base[(size_t)i * cD4];
                ax += a0.x; ay += a0.y; az += a0.z; aw += a0.w;
            }
            wgt = 1.0f / (float)len;
        } else {
            // candidate node: mean over CSR contribution list
            const int j0 = offs[row], j1 = offs[row + 1];
            if (j1 > j0) {
                int j = j0;
                for (; j + 4 <= j1; j += 4) {
                    const float4 a0 = emb[(size_t)idx[j + 0] * cD4 + tid];
                    const float4 a1 = emb[(size_t)idx[j + 1] * cD4 + tid];
                    const float4 a2 = emb[(size_t)idx[j + 2] * cD4 + tid];
                    const float4 a3 = emb[(size_t)idx[j + 3] * cD4 + tid];
                    ax += (a0.x + a1.x) + (a2.x + a3.x);
                    ay += (a0.y + a1.y) + (a2.y + a3.y);
                    az += (a0.z + a1.z) + (a2.z + a3.z);
                    aw += (a0.w + a1.w) + (a2.w + a3.w);
                }
                for (; j < j1; ++j) {
                    const float4 a0 = emb[(size_t)idx[j] * cD4 + tid];
                    ax += a0.x; ay += a0.y; az += a0.z; aw += a0.w;
                }
                wgt = 1.0f / (float)(j1 - j0);
            }
        }
    }

    const int sid = step_ids[row];
    const float4 se = step_tab[(size_t)sid * cD4 + tid];
    const float4 g  = ln_g[tid];
    const float4 bb = ln_b[tid];
    float4 o;
    o.x = (x.x - mu) * rs * g.x + bb.x + se.x + ax * wgt;
    o.y = (x.y - mu) * rs * g.y + bb.y + se.y + ay * wgt;
    o.z = (x.z - mu) * rs * g.z + bb.z + se.z + az * wgt;
    o.w = (x.w - mu) * rs * g.w + bb.w + se.w + aw * wgt;
    out[(size_t)row * cD4 + tid] = o;
}

// ---------------------------------------------------------------------------
extern "C" void kernel_launch(void* const* d_in, const int* in_sizes, int n_in,
                              void* d_out, int out_size, void* d_ws, size_t ws_size,
                              hipStream_t stream) {
    const float* emb      = (const float*)d_in[0];   // [B,T,V,D]
    const float* pos_fts  = (const float*)d_in[1];   // [B,N,7]
    const float* step_tab = (const float*)d_in[2];   // [100,D]
    const float* pos_w    = (const float*)d_in[3];   // [7,D]
    const float* pos_b    = (const float*)d_in[4];   // [D]
    const float* ln_g     = (const float*)d_in[5];   // [D]
    const float* ln_b     = (const float*)d_in[6];   // [D]
    const int*   vp_lens  = (const int*)d_in[7];     // [B,T]
    const int*   vpids    = (const int*)d_in[8];     // [B,T]
    const int*   cand     = (const int*)d_in[9];     // [B,T,V]
    const int*   step_ids = (const int*)d_in[10];    // [B,N]
    // d_in[11] = gmap_lens — unused by the reference output

    float4* out = (float4*)d_out;

    // ws layout: cnt[5120] | offs[5121] | cur[5120] | idx[48000]
    int* cnt  = (int*)d_ws;
    int* offs = cnt + cBN;
    int* cur  = offs + (cBN + 1);
    int* idx  = cur + cBN;

    (void)hipMemsetAsync(cnt, 0, cBN * sizeof(int), stream);
    k_count<<<cB * cT, 128, 0, stream>>>(vp_lens, vpids, cand, cnt);
    k_scan <<<1, 1024, 0, stream>>>(cnt, offs, cur);
    k_fill <<<cB * cT, 128, 0, stream>>>(vp_lens, vpids, cand, cur, idx);
    k_fused<<<cBN, 192, 0, stream>>>((const float4*)emb, pos_fts,
                                     (const float4*)step_tab,
                                     (const float4*)pos_w, (const float4*)pos_b,
                                     (const float4*)ln_g, (const float4*)ln_b,
                                     vp_lens, vpids, step_ids, offs, idx, out);
}

// Round 4
// 36.980 us; speedup vs baseline: 6.8389x; 1.3694x over previous
//
#include <hip/hip_runtime.h>

// Problem dims (fixed by the reference)
constexpr int cB = 32, cT = 15, cV = 100, cD = 768, cN = 160, cAP = 7;
constexpr int cD4 = cD / 4;         // 192 float4 per row
constexpr int cTV = cT * cV;        // 1500 candidate entries per batch
constexpr float cLN_EPS = 1e-12f;

// One block per output row (b,n): pos-GEMV + LayerNorm + step emb + image gather.
// Candidate contributor lists are built in-block by scanning the batch's
// cand_ids (L2-resident) -> no prep kernels, no workspace.
__global__ __launch_bounds__(192) void k_all(
    const float4* __restrict__ emb,      // [B*T*V, D/4]
    const float*  __restrict__ pos_fts,  // [B,N,7]
    const float4* __restrict__ step_tab, // [100, D/4]
    const float4* __restrict__ pos_w,    // [7, D/4]
    const float4* __restrict__ pos_b,    // [D/4]
    const float4* __restrict__ ln_g,     // [D/4]
    const float4* __restrict__ ln_b,     // [D/4]
    const int*    __restrict__ vp_lens,  // [B,T]
    const int*    __restrict__ vpids,    // [B,T]
    const int*    __restrict__ cand_ids, // [B,T,V]
    const int*    __restrict__ step_ids, // [B,N]
    float4*       __restrict__ out)      // [B*N, D/4]
{
    const int n   = blockIdx.x;          // node id 0..159
    const int b   = blockIdx.y;          // batch 0..31
    const int row = b * cN + n;
    const int tid = threadIdx.x;         // 0..191, owns float4 slot tid

    __shared__ float sf[cAP];
    __shared__ int   slen[cT];
    __shared__ int   svp[cT];
    __shared__ float red[8];
    __shared__ int   scount;
    __shared__ int   slist[cTV];         // contributor entries (t*V+v), 6 KB

    if (tid < cAP) sf[tid] = pos_fts[row * cAP + tid];
    if (tid >= 32 && tid < 32 + cT) slen[tid - 32] = vp_lens[b * cT + (tid - 32)];
    if (tid >= 64 && tid < 64 + cT) svp[tid - 64]  = vpids[b * cT + (tid - 64)];
    if (tid == 0) scount = 0;
    __syncthreads();

    // ---- pos GEMV: 4 outputs per thread ----
    float4 x = pos_b[tid];
#pragma unroll
    for (int k = 0; k < cAP; ++k) {
        const float4 w = pos_w[k * cD4 + tid];
        const float f = sf[k];
        x.x = fmaf(f, w.x, x.x); x.y = fmaf(f, w.y, x.y);
        x.z = fmaf(f, w.z, x.z); x.w = fmaf(f, w.w, x.w);
    }
    float s  = x.x + x.y + x.z + x.w;
    float ss = x.x * x.x + x.y * x.y + x.z * x.z + x.w * x.w;
    for (int off = 32; off; off >>= 1) {
        s  += __shfl_down(s,  off, 64);
        ss += __shfl_down(ss, off, 64);
    }
    const int wid = tid >> 6, lane = tid & 63;
    if (lane == 0) { red[wid * 2] = s; red[wid * 2 + 1] = ss; }
    __syncthreads();
    if (tid == 0) {
        float S = 0.f, SS = 0.f;
        for (int w = 0; w < 3; ++w) { S += red[w * 2]; SS += red[w * 2 + 1]; }
        const float mu  = S / (float)cD;
        const float var = SS / (float)cD - mu * mu;
        red[6] = mu;
        red[7] = rsqrtf(fmaxf(var, 0.f) + cLN_EPS);
    }
    __syncthreads();
    const float mu = red[6], rs = red[7];

    // ---- gather image feature for this node ----
    float ax = 0.f, ay = 0.f, az = 0.f, aw = 0.f;
    float wgt = 0.f;
    if (n > 0) {
        int tvis = -1;
#pragma unroll
        for (int k = cT - 1; k >= 0; --k) if (tvis < 0 && svp[k] == n) tvis = k;
        if (tvis >= 0) {
            // visited node: mean over valid views of step tvis
            const int bt  = b * cT + tvis;
            const int len = slen[tvis];
            const float4* base = emb + (size_t)bt * cV * cD4 + tid;
            int i = 0;
            for (; i + 4 <= len; i += 4) {
                const float4 a0 = base[(size_t)(i + 0) * cD4];
                const float4 a1 = base[(size_t)(i + 1) * cD4];
                const float4 a2 = base[(size_t)(i + 2) * cD4];
                const float4 a3 = base[(size_t)(i + 3) * cD4];
                ax += (a0.x + a1.x) + (a2.x + a3.x);
                ay += (a0.y + a1.y) + (a2.y + a3.y);
                az += (a0.z + a1.z) + (a2.z + a3.z);
                aw += (a0.w + a1.w) + (a2.w + a3.w);
            }
            for (; i < len; ++i) {
                const float4 a0 = base[(size_t)i * cD4];
                ax += a0.x; ay += a0.y; az += a0.z; aw += a0.w;
            }
            wgt = 1.0f / (float)len;
        } else {
            // candidate node: scan this batch's cand ids, compact matches
            const int* cb = cand_ids + (size_t)b * cTV;
            for (int e = tid; e < cTV; e += 192) {
                const int t = e / cV;          // magic-mul division
                const int v = e - t * cV;
                if (v < slen[t] && cb[e] == n) {
                    const int p = atomicAdd(&scount, 1);
                    slist[p] = e;
                }
            }
            __syncthreads();
            const int m = scount;
            const float4* base = emb + (size_t)b * cTV * cD4 + tid;
            int j = 0;
            for (; j + 4 <= m; j += 4) {
                const float4 a0 = base[(size_t)slist[j + 0] * cD4];
                const float4 a1 = base[(size_t)slist[j + 1] * cD4];
                const float4 a2 = base[(size_t)slist[j + 2] * cD4];
                const float4 a3 = base[(size_t)slist[j + 3] * cD4];
                ax += (a0.x + a1.x) + (a2.x + a3.x);
                ay += (a0.y + a1.y) + (a2.y + a3.y);
                az += (a0.z + a1.z) + (a2.z + a3.z);
                aw += (a0.w + a1.w) + (a2.w + a3.w);
            }
            for (; j < m; ++j) {
                const float4 a0 = base[(size_t)slist[j] * cD4];
                ax += a0.x; ay += a0.y; az += a0.z; aw += a0.w;
            }
            if (m > 0) wgt = 1.0f / (float)m;
        }
    }

    const int sid = step_ids[row];
    const float4 se = step_tab[(size_t)sid * cD4 + tid];
    const float4 g  = ln_g[tid];
    const float4 bb = ln_b[tid];
    float4 o;
    o.x = (x.x - mu) * rs * g.x + bb.x + se.x + ax * wgt;
    o.y = (x.y - mu) * rs * g.y + bb.y + se.y + ay * wgt;
    o.z = (x.z - mu) * rs * g.z + bb.z + se.z + az * wgt;
    o.w = (x.w - mu) * rs * g.w + bb.w + se.w + aw * wgt;
    out[(size_t)row * cD4 + tid] = o;
}

// ---------------------------------------------------------------------------
extern "C" void kernel_launch(void* const* d_in, const int* in_sizes, int n_in,
                              void* d_out, int out_size, void* d_ws, size_t ws_size,
                              hipStream_t stream) {
    const float* emb      = (const float*)d_in[0];   // [B,T,V,D]
    const float* pos_fts  = (const float*)d_in[1];   // [B,N,7]
    const float* step_tab = (const float*)d_in[2];   // [100,D]
    const float* pos_w    = (const float*)d_in[3];   // [7,D]
    const float* pos_b    = (const float*)d_in[4];   // [D]
    const float* ln_g     = (const float*)d_in[5];   // [D]
    const float* ln_b     = (const float*)d_in[6];   // [D]
    const int*   vp_lens  = (const int*)d_in[7];     // [B,T]
    const int*   vpids    = (const int*)d_in[8];     // [B,T]
    const int*   cand     = (const int*)d_in[9];     // [B,T,V]
    const int*   step_ids = (const int*)d_in[10];    // [B,N]
    // d_in[11] = gmap_lens — unused by the reference output

    dim3 grid(cN, cB);
    k_all<<<grid, 192, 0, stream>>>((const float4*)emb, pos_fts,
                                    (const float4*)step_tab,
                                    (const float4*)pos_w, (const float4*)pos_b,
                                    (const float4*)ln_g, (const float4*)ln_b,
                                    vp_lens, vpids, cand, step_ids,
                                    (float4*)d_out);
}